// Round 5
// baseline (205.512 us; speedup 1.0000x reference)
//
#include <hip/hip_runtime.h>

#define B_TOT 8192
#define NB    16         // batch elements per block
#define NPCS  20

typedef __attribute__((ext_vector_type(8))) short bf16x8;
typedef __attribute__((ext_vector_type(4))) float f32x4;
typedef __attribute__((ext_vector_type(2))) float f32x2;
typedef __attribute__((ext_vector_type(2))) __fp16 fp16x2;

__device__ __forceinline__ short f2bf(float f) {
    union { float f; unsigned u; } v; v.f = f;
    unsigned r = v.u + 0x7FFFu + ((v.u >> 16) & 1u);  // RNE
    return (short)(r >> 16);
}
__device__ __forceinline__ unsigned pkmax(unsigned a, unsigned b) {
    unsigned d; asm("v_pk_max_f16 %0, %1, %2" : "=v"(d) : "v"(a), "v"(b)); return d;
}
__device__ __forceinline__ unsigned pkmin(unsigned a, unsigned b) {
    unsigned d; asm("v_pk_min_f16 %0, %1, %2" : "=v"(d) : "v"(a), "v"(b)); return d;
}
__device__ __forceinline__ float h2f(unsigned u) {   // converts low 16 bits
    float f; asm("v_cvt_f32_f16 %0, %1" : "=v"(f) : "v"(u)); return f;
}
__device__ __forceinline__ unsigned pkrtz(float a, float b) {
    fp16x2 h = __builtin_amdgcn_cvt_pkrtz(a, b);     // lo=a, hi=b
    return __builtin_bit_cast(unsigned, h);
}
__device__ __forceinline__ float asf(unsigned u) { return __builtin_bit_cast(float, u); }
__device__ __forceinline__ unsigned asu(float f) { return __builtin_bit_cast(unsigned, f); }
// pack bf16-trunc(a) -> lo, bf16-trunc(b) -> hi
__device__ __forceinline__ unsigned packtr(float a, float b) {
    return (asu(a) >> 16) | (asu(b) & 0xffff0000u);
}

// lane-xor exchange within 16-lane DPP rows; lm constant-folded in unrolled loops.
template<int CTRL>
__device__ __forceinline__ unsigned dppmov(unsigned v) {
    return (unsigned)__builtin_amdgcn_mov_dpp((int)v, CTRL, 0xf, 0xf, true);
}
__device__ __forceinline__ unsigned xlane(unsigned v, int lm) {
    switch (lm) {
    case 1:  return dppmov<0xB1>(v);    // quad_perm [1,0,3,2]  = xor 1
    case 2:  return dppmov<0x4E>(v);    // quad_perm [2,3,0,1]  = xor 2
    case 4:  return (unsigned)__builtin_amdgcn_ds_swizzle((int)v, 0x101F); // xor 4
    default: return dppmov<0x128>(v);   // row_ror:8 == xor 8 within 16-lane row
    }
}
__device__ __forceinline__ float xlanef(float v, int lm) { return asf(xlane(asu(v), lm)); }

// ---------------- d_ws layout (bytes) ----------------
// [0,     32768): W2T bf16 [128][128]   w2t[j*128+k] = bf16(W2[k][j])
// [32768, 40960): W3T bf16 [32][128]    w3t[c*128+k] = bf16(W3[k][c])
// [40960, 57344): wsp f32  [32][128]    precomputed fspool weights
// [57344, 59392): w1p uint4 [128]       per h-pair hp: u[k] = bf16(W1[k][2hp]) | bf16(W1[k][2hp+1])<<16
#define WS_W3T 32768
#define WS_WSP 40960
#define WS_W1P 57344

__global__ void prep_kernel(const float* __restrict__ W1, const float* __restrict__ W2,
                            const float* __restrict__ W3, const float* __restrict__ pw,
                            void* __restrict__ ws)
{
    const int t = blockIdx.x * 256 + threadIdx.x;
    short* w2t = (short*)ws;
    short* w3t = (short*)((char*)ws + WS_W3T);
    float* wsp = (float*)((char*)ws + WS_WSP);
    uint4* w1p = (uint4*)((char*)ws + WS_W1P);
    if (t < 16384) {
        int j = t >> 7, k = t & 127;
        w2t[t] = f2bf(W2[k * 128 + j]);
    } else if (t < 20480) {
        int o = t - 16384, c = o >> 7, k = o & 127;
        w3t[o] = f2bf(W3[k * 32 + c]);
    } else if (t < 24576) {
        int o = t - 20480, c = o >> 7, p = o & 127;
        float pos = (float)p * (20.0f / 127.0f);
        int ip = min((int)pos, NPCS);
        float fr = pos - (float)ip;
        int ipb = min(ip + 1, NPCS);
        wsp[o] = (1.0f - fr) * pw[c * 21 + ip] + fr * pw[c * 21 + ipb];
    } else if (t < 24704) {
        int hp = t - 24576;              // h-pair index, h = 2hp, 2hp+1
        uint4 u;
        unsigned* uu = (unsigned*)&u;
#pragma unroll
        for (int k = 0; k < 4; ++k) {
            unsigned lo = (unsigned short)f2bf(W1[k * 128 + 2 * hp]);
            unsigned hi = (unsigned short)f2bf(W1[k * 128 + 2 * hp + 1]);
            uu[k] = lo | (hi << 16);
        }
        w1p[hp] = u;
    }
}

// ---------------- LDS layout (bytes, total 46848) ----------------
// [0,     16384): sW2T bf16 rows 64..127 (nt 4-7), rows 256 B, chunk phys = ch ^ (row&15)
// [16384, 33792): scr  bf16, per-wave 16 x 136 shorts
// [33792, 42240): szp  uint [16][132]  packed-f16 z pairs
// [42240, 44288): sw1p uint4 [128]
// [44288, 44800): sb1  f32[128]
// [44800, 46848): spool f32[NB*32]
#define L_SCR  16384
#define L_SZP  33792
#define L_W1P  42240
#define L_B1   44288
#define L_POOL 44800

__global__ __launch_bounds__(256, 2) void enc_kernel(
    const float* __restrict__ x,   const float* __restrict__ b1g,
    const float* __restrict__ b2g, const float* __restrict__ b3g,
    const float* __restrict__ eps, const void* __restrict__ ws,
    float* __restrict__ out)
{
    __shared__ __align__(16) char smem[46848];

    const int tid  = threadIdx.x;
    const int wv   = tid >> 6;
    const int lane = tid & 63;
    const int l16  = lane & 15;     // lane-within-group for the sort
    const int quad = lane >> 4;
    const int b0   = blockIdx.x * NB;

    // ---------- stage sW2T rows 64-127 (xor-swizzled), w1p, b1 ----------
    {
        const uint4* src = (const uint4*)ws;     // 16B chunks; rows 64.. start at chunk 1024
#pragma unroll
        for (int it = 0; it < 4; ++it) {
            int idx = tid + it * 256;            // 0..1023
            int row = idx >> 4, ch = idx & 15;   // local row 0..63 (= j-64); j&15 == row&15
            *(uint4*)(smem + row * 256 + ((ch ^ (row & 15)) * 16)) = src[idx + 1024];
        }
    }
    if (tid < 128) ((uint4*)(smem + L_W1P))[tid] = ((const uint4*)((const char*)ws + WS_W1P))[tid];
    if (tid < 32)  ((float4*)(smem + L_B1))[tid] = ((const float4*)b1g)[tid];

    // ---------- hoisted register-resident data (persist across NB elements) ----------
    const short* w2tg = (const short*)ws;
    bf16x8 w2c[4][4];                                  // W2T B-frags, nt 0..3 (64 VGPR)
#pragma unroll
    for (int nt = 0; nt < 4; ++nt)
#pragma unroll
        for (int kt = 0; kt < 4; ++kt)
            w2c[nt][kt] = *(const bf16x8*)(w2tg + (nt * 16 + l16) * 128 + kt * 32 + quad * 8);

    bf16x8 w3f[2][4];                                  // W3T A-frags
    {
        const short* w3t = (const short*)((const char*)ws + WS_W3T);
#pragma unroll
        for (int mt2 = 0; mt2 < 2; ++mt2)
#pragma unroll
            for (int kt = 0; kt < 4; ++kt)
                w3f[mt2][kt] = *(const bf16x8*)(w3t + (mt2 * 16 + l16) * 128 + kt * 32 + quad * 8);
    }
    float4 b3v[2];
    b3v[0] = *(const float4*)(b3g + quad * 4);
    b3v[1] = *(const float4*)(b3g + 16 + quad * 4);
    float b2r[8];
#pragma unroll
    for (int nt = 0; nt < 8; ++nt) b2r[nt] = b2g[nt * 16 + l16];

    // fspool weights for this lane's pair-row (element-invariant)
    const int pr = wv * 4 + quad;    // packed pair-row: channels 2pr (mu), 2pr+1 (logvar)
    float wE[8], wO[8];
    {
        const float* wsp = (const float*)((const char*)ws + WS_WSP);
        float4 e0 = *(const float4*)(wsp + (2 * pr) * 128 + l16 * 8);
        float4 e1 = *(const float4*)(wsp + (2 * pr) * 128 + l16 * 8 + 4);
        float4 o0 = *(const float4*)(wsp + (2 * pr + 1) * 128 + l16 * 8);
        float4 o1 = *(const float4*)(wsp + (2 * pr + 1) * 128 + l16 * 8 + 4);
        wE[0]=e0.x; wE[1]=e0.y; wE[2]=e0.z; wE[3]=e0.w; wE[4]=e1.x; wE[5]=e1.y; wE[6]=e1.z; wE[7]=e1.w;
        wO[0]=o0.x; wO[1]=o0.y; wO[2]=o0.z; wO[3]=o0.w; wO[4]=o1.x; wO[5]=o1.y; wO[6]=o1.z; wO[7]=o1.w;
    }
    __syncthreads();

    short*    scr   = (short*)(smem + L_SCR) + wv * (16 * 136);
    unsigned* szp   = (unsigned*)(smem + L_SZP);       // stride 132
    const uint4* sw1p = (const uint4*)(smem + L_W1P);
    const float* sb1 = (const float*)(smem + L_B1);
    float*    spool = (float*)(smem + L_POOL);

    for (int e = 0; e < NB; ++e) {
        const int b = b0 + e;

        // ---------- GEMM1 (pk-f32 VALU, K=4): h1 A-frags ----------
        const float4 xv0 = *(const float4*)(x + (size_t)b * 512 + (wv * 32 + l16) * 4);
        const float4 xv1 = *(const float4*)(x + (size_t)b * 512 + (wv * 32 + 16 + l16) * 4);
        const f32x2 xbA[4] = {{xv0.x, xv0.x}, {xv0.y, xv0.y}, {xv0.z, xv0.z}, {xv0.w, xv0.w}};
        const f32x2 xbB[4] = {{xv1.x, xv1.x}, {xv1.y, xv1.y}, {xv1.z, xv1.z}, {xv1.w, xv1.w}};
        union AF { unsigned u[4]; bf16x8 v; } a1[2][4];
#pragma unroll
        for (int kt = 0; kt < 4; ++kt) {
#pragma unroll
            for (int jj = 0; jj < 4; ++jj) {
                const int hp = kt * 16 + quad * 4 + jj;   // h-pair (2hp, 2hp+1)
                const uint4 wp = sw1p[hp];
                const f32x2 bp = *(const f32x2*)(sb1 + 2 * hp);
                f32x2 accA = bp, accB = bp;
                const unsigned wk[4] = {wp.x, wp.y, wp.z, wp.w};
#pragma unroll
                for (int k = 0; k < 4; ++k) {
                    f32x2 w2v;
                    w2v.x = asf(wk[k] << 16);
                    w2v.y = asf(wk[k] & 0xffff0000u);
                    accA = __builtin_elementwise_fma(w2v, xbA[k], accA);
                    accB = __builtin_elementwise_fma(w2v, xbB[k], accB);
                }
                a1[0][kt].u[jj] = packtr(fmaxf(accA.x, 0.f), fmaxf(accA.y, 0.f));
                a1[1][kt].u[jj] = packtr(fmaxf(accB.x, 0.f), fmaxf(accB.y, 0.f));
            }
        }

        // ---------- GEMM2 (MFMA): h2 = relu(h1 @ W2 + b2), bias pre-seeded ----------
        f32x4 acc2[2][8];
#pragma unroll
        for (int mt = 0; mt < 2; ++mt)
#pragma unroll
            for (int nt = 0; nt < 8; ++nt)
                acc2[mt][nt] = (f32x4){b2r[nt], b2r[nt], b2r[nt], b2r[nt]};
#pragma unroll
        for (int kt = 0; kt < 4; ++kt) {
#pragma unroll
            for (int nt = 0; nt < 8; ++nt) {
                bf16x8 bf;
                if (nt < 4) {
                    bf = w2c[nt][kt];
                } else {
                    const int jl = (nt - 4) * 16 + l16;           // local row, j = jl+64
                    bf = *(const bf16x8*)(smem + jl * 256 + (((kt * 4 + quad) ^ l16) * 16));
                }
                acc2[0][nt] = __builtin_amdgcn_mfma_f32_16x16x32_bf16(a1[0][kt].v, bf, acc2[0][nt], 0, 0, 0);
                acc2[1][nt] = __builtin_amdgcn_mfma_f32_16x16x32_bf16(a1[1][kt].v, bf, acc2[1][nt], 0, 0, 0);
            }
        }

        // ---------- GEMM3 transposed: z = W3T @ h2^T (+b3), via per-wave scr ----------
#pragma unroll
        for (int mt = 0; mt < 2; ++mt) {
#pragma unroll
            for (int nt = 0; nt < 8; ++nt) {
                const int col = nt * 16 + l16;
#pragma unroll
                for (int r = 0; r < 4; ++r)
                    scr[(quad * 4 + r) * 136 + col] = (short)(asu(fmaxf(acc2[mt][nt][r], 0.0f)) >> 16);
            }
            asm volatile("s_waitcnt lgkmcnt(0)" ::: "memory");  // wave-local scr RAW

            bf16x8 a3[4];
#pragma unroll
            for (int kt = 0; kt < 4; ++kt)
                a3[kt] = *(const bf16x8*)(scr + l16 * 136 + kt * 32 + quad * 8);

            const int colbase = wv * 32 + mt * 16;
#pragma unroll
            for (int mt2 = 0; mt2 < 2; ++mt2) {
                f32x4 acc = (f32x4){b3v[mt2].x, b3v[mt2].y, b3v[mt2].z, b3v[mt2].w};
#pragma unroll
                for (int kt = 0; kt < 4; ++kt)
                    acc = __builtin_amdgcn_mfma_f32_16x16x32_bf16(w3f[mt2][kt], a3[kt], acc, 0, 0, 0);
                // lane holds z rows c = 16*mt2 + 4*quad + r, col p = colbase + l16
                const int prw = 8 * mt2 + 2 * quad;
                szp[prw * 132 + colbase + l16]       = pkrtz(acc[0], acc[1]);  // lo=even c (mu ch)
                szp[(prw + 1) * 132 + colbase + l16] = pkrtz(acc[2], acc[3]);
            }
            asm volatile("" ::: "memory");  // keep a3 reads ahead of next-mt scr writes
        }
        __syncthreads();  // all waves' z columns visible

        // ---------- packed-f16 bitonic sort, 8 elems/lane over 16-lane groups ----------
        // group = quad; virtual element index i = l16*8 + r; full sort => input order free
        unsigned v[8];
        {
            const unsigned* zp = szp + pr * 132 + l16 * 8;
            uint4 za = *(const uint4*)zp;
            uint4 zb = *(const uint4*)(zp + 4);
            v[0]=za.x; v[1]=za.y; v[2]=za.z; v[3]=za.w;
            v[4]=zb.x; v[5]=zb.y; v[6]=zb.z; v[7]=zb.w;
        }
        const int ib = l16 * 8;
#pragma unroll
        for (int k = 2; k <= 128; k <<= 1) {
#pragma unroll
            for (int j = 64; j >= 1; j >>= 1) {
                if (j >= k) continue;
                if (j >= 8) {                       // cross-lane (within 16-lane DPP row)
                    const bool km = ((ib & k) == 0) != ((ib & j) != 0);
                    const int lm = j >> 3;
#pragma unroll
                    for (int r = 0; r < 8; ++r) {
                        unsigned p = xlane(v[r], lm);
                        unsigned mx = pkmax(v[r], p), mn = pkmin(v[r], p);
                        v[r] = km ? mx : mn;
                    }
                } else if (k <= 4) {                // in-lane, static direction
#pragma unroll
                    for (int a = 0; a < 8; ++a) {
                        if (a & j) continue;
                        const int bx = a | j;
                        unsigned mx = pkmax(v[a], v[bx]), mn = pkmin(v[a], v[bx]);
                        if ((a & k) == 0) { v[a] = mx; v[bx] = mn; }
                        else              { v[a] = mn; v[bx] = mx; }
                    }
                } else {                            // in-lane, lane-dependent direction
                    const bool km = ((ib & k) == 0);
#pragma unroll
                    for (int a = 0; a < 8; ++a) {
                        if (a & j) continue;
                        const int bx = a | j;
                        unsigned mx = pkmax(v[a], v[bx]), mn = pkmin(v[a], v[bx]);
                        v[a] = km ? mx : mn;
                        v[bx] = km ? mn : mx;
                    }
                }
            }
        }

        // ---------- weighted sum + 16-lane group reduction (DPP) ----------
        float sE = 0.f, sO = 0.f;
#pragma unroll
        for (int r = 0; r < 8; ++r) {
            sE = fmaf(wE[r], h2f(v[r]), sE);
            sO = fmaf(wO[r], h2f(v[r] >> 16), sO);
        }
#pragma unroll
        for (int d = 8; d >= 1; d >>= 1) {
            sE += xlanef(sE, d);
            sO += xlanef(sO, d);
        }
        if (l16 == 0) {
            spool[e * 32 + 2 * pr]     = sE;
            spool[e * 32 + 2 * pr + 1] = sO;
        }
        __syncthreads();  // spool ready; protects szp WAR for next element
    }

    // ---------- batched coalesced epilogue (NB*16 == 256) ----------
    {
        const int e = tid >> 4, t = tid & 15;
        const float mu = spool[e * 32 + 2 * t];
        const float lv = spool[e * 32 + 2 * t + 1];
        const float ev = eps[(size_t)b0 * 16 + tid];
        const float smp = fmaf(ev, __expf(0.5f * lv), mu);
        out[(size_t)b0 * 16 + tid] = mu;
        out[(size_t)B_TOT * 16 + (size_t)b0 * 16 + tid] = lv;
        out[(size_t)2 * B_TOT * 16 + (size_t)b0 * 16 + tid] = smp;
    }
}

extern "C" void kernel_launch(void* const* d_in, const int* in_sizes, int n_in,
                              void* d_out, int out_size, void* d_ws, size_t ws_size,
                              hipStream_t stream) {
    const float* x   = (const float*)d_in[0];
    const float* W1  = (const float*)d_in[1];
    const float* b1  = (const float*)d_in[2];
    const float* W2  = (const float*)d_in[3];
    const float* b2  = (const float*)d_in[4];
    const float* W3  = (const float*)d_in[5];
    const float* b3  = (const float*)d_in[6];
    const float* pw  = (const float*)d_in[7];
    const float* eps = (const float*)d_in[8];
    float* out = (float*)d_out;

    prep_kernel<<<dim3(97), dim3(256), 0, stream>>>(W1, W2, W3, pw, d_ws);
    enc_kernel<<<dim3(B_TOT / NB), dim3(256), 0, stream>>>(x, b1, b2, b3, eps, d_ws, out);
}

// Round 8
// 181.241 us; speedup vs baseline: 1.1339x; 1.1339x over previous
//
#include <hip/hip_runtime.h>

#define B_TOT 8192
#define NB    16         // batch elements per block
#define NPCS  20

typedef __attribute__((ext_vector_type(8))) short bf16x8;
typedef __attribute__((ext_vector_type(4))) float f32x4;
typedef __attribute__((ext_vector_type(2))) __fp16 fp16x2;

__device__ __forceinline__ short f2bf(float f) {
    union { float f; unsigned u; } v; v.f = f;
    unsigned r = v.u + 0x7FFFu + ((v.u >> 16) & 1u);  // RNE
    return (short)(r >> 16);
}
__device__ __forceinline__ unsigned pkmax(unsigned a, unsigned b) {
    unsigned d; asm("v_pk_max_f16 %0, %1, %2" : "=v"(d) : "v"(a), "v"(b)); return d;
}
__device__ __forceinline__ unsigned pkmin(unsigned a, unsigned b) {
    unsigned d; asm("v_pk_min_f16 %0, %1, %2" : "=v"(d) : "v"(a), "v"(b)); return d;
}
__device__ __forceinline__ float h2f(unsigned u) {   // converts low 16 bits
    float f; asm("v_cvt_f32_f16 %0, %1" : "=v"(f) : "v"(u)); return f;
}
// RNE f16 pack via compiler-generated casts (default FP rounding = RNE):
// lo = rne_f16(a), hi = rne_f16(b)
__device__ __forceinline__ unsigned pkrne(float a, float b) {
    fp16x2 h;
    h.x = (__fp16)a;
    h.y = (__fp16)b;
    return __builtin_bit_cast(unsigned, h);
}
__device__ __forceinline__ float asf(unsigned u) { return __builtin_bit_cast(float, u); }
__device__ __forceinline__ unsigned asu(float f) { return __builtin_bit_cast(unsigned, f); }
// pack bf16-trunc(a) -> lo, bf16-trunc(b) -> hi
__device__ __forceinline__ unsigned packtr(float a, float b) {
    return (asu(a) >> 16) | (asu(b) & 0xffff0000u);
}

// lane-xor exchange within 16-lane DPP rows; lm constant-folded in unrolled loops.
template<int CTRL>
__device__ __forceinline__ unsigned dppmov(unsigned v) {
    return (unsigned)__builtin_amdgcn_mov_dpp((int)v, CTRL, 0xf, 0xf, true);
}
__device__ __forceinline__ unsigned xlane(unsigned v, int lm) {
    switch (lm) {
    case 1:  return dppmov<0xB1>(v);    // quad_perm [1,0,3,2]  = xor 1
    case 2:  return dppmov<0x4E>(v);    // quad_perm [2,3,0,1]  = xor 2
    case 4:  return (unsigned)__builtin_amdgcn_ds_swizzle((int)v, 0x101F); // xor 4
    default: return dppmov<0x128>(v);   // row_ror:8 == xor 8 within 16-lane row
    }
}
__device__ __forceinline__ float xlanef(float v, int lm) { return asf(xlane(asu(v), lm)); }

// ---------------- d_ws layout (bytes) ----------------
// [0,     32768): W2T bf16 [128][128]   w2t[j*128+k] = bf16(W2[k][j])
// [32768, 40960): W3T bf16 [32][128]    w3t[c*128+k] = bf16(W3[k][c])
// [40960, 57344): wsp f32  [32][128]    precomputed fspool weights
// [57344, 58368): w1b bf16x4 [128]      per h: {W1[0][h],W1[1][h],W1[2][h],W1[3][h]}
#define WS_W3T 32768
#define WS_WSP 40960
#define WS_W1B 57344

__global__ void prep_kernel(const float* __restrict__ W1, const float* __restrict__ W2,
                            const float* __restrict__ W3, const float* __restrict__ pw,
                            void* __restrict__ ws)
{
    const int t = blockIdx.x * 256 + threadIdx.x;
    short* w2t = (short*)ws;
    short* w3t = (short*)((char*)ws + WS_W3T);
    float* wsp = (float*)((char*)ws + WS_WSP);
    short* w1b = (short*)((char*)ws + WS_W1B);
    if (t < 16384) {
        int j = t >> 7, k = t & 127;
        w2t[t] = f2bf(W2[k * 128 + j]);
    } else if (t < 20480) {
        int o = t - 16384, c = o >> 7, k = o & 127;
        w3t[o] = f2bf(W3[k * 32 + c]);
    } else if (t < 24576) {
        int o = t - 20480, c = o >> 7, p = o & 127;
        float pos = (float)p * (20.0f / 127.0f);
        int ip = min((int)pos, NPCS);
        float fr = pos - (float)ip;
        int ipb = min(ip + 1, NPCS);
        wsp[o] = (1.0f - fr) * pw[c * 21 + ip] + fr * pw[c * 21 + ipb];
    } else if (t < 24704) {
        int h = t - 24576;
        w1b[h * 4 + 0] = f2bf(W1[h]);
        w1b[h * 4 + 1] = f2bf(W1[128 + h]);
        w1b[h * 4 + 2] = f2bf(W1[256 + h]);
        w1b[h * 4 + 3] = f2bf(W1[384 + h]);
    }
}

// ---------------- LDS layout (bytes, total 62208) ----------------
// [0,     32768): sW2T bf16, rows 256 B, chunk phys = ch ^ (row&15)  (xor swizzle)
// [32768, 50176): scr  bf16, per-wave 16 x 136 shorts
// [50176, 58624): szp  uint [16][132]  packed-f16 z pairs
// [58624, 59648): sw1b bf16x4 [128]
// [59648, 60160): sb1  f32[128]
// [60160, 62208): spool f32[NB*32]
#define L_SCR  32768
#define L_SZP  50176
#define L_W1B  58624
#define L_B1   59648
#define L_POOL 60160

__global__ __launch_bounds__(256, 2) void enc_kernel(
    const float* __restrict__ x,   const float* __restrict__ b1g,
    const float* __restrict__ b2g, const float* __restrict__ b3g,
    const float* __restrict__ eps, const void* __restrict__ ws,
    float* __restrict__ out)
{
    __shared__ __align__(16) char smem[62208];

    const int tid  = threadIdx.x;
    const int wv   = tid >> 6;
    const int lane = tid & 63;
    const int l16  = lane & 15;     // lane-within-group for the sort
    const int quad = lane >> 4;
    const int b0   = blockIdx.x * NB;

    // ---------- stage sW2T (xor-swizzled), w1b, b1 ----------
    {
        const uint4* src = (const uint4*)ws;     // 2048 16B chunks
#pragma unroll
        for (int it = 0; it < 8; ++it) {
            int idx = tid + it * 256;
            int j = idx >> 4, ch = idx & 15;
            *(uint4*)(smem + j * 256 + ((ch ^ (j & 15)) * 16)) = src[idx];
        }
    }
    if (tid < 64)  ((uint4*)(smem + L_W1B))[tid] = ((const uint4*)((const char*)ws + WS_W1B))[tid];
    if (tid < 32)  ((float4*)(smem + L_B1))[tid] = ((const float4*)b1g)[tid];

    // ---------- hoisted register-resident data (persist across NB elements) ----------
    bf16x8 w3f[2][4];                                  // W3T A-frags
    {
        const short* w3t = (const short*)((const char*)ws + WS_W3T);
#pragma unroll
        for (int mt2 = 0; mt2 < 2; ++mt2)
#pragma unroll
            for (int kt = 0; kt < 4; ++kt)
                w3f[mt2][kt] = *(const bf16x8*)(w3t + (mt2 * 16 + l16) * 128 + kt * 32 + quad * 8);
    }
    float4 b3v[2];
    b3v[0] = *(const float4*)(b3g + quad * 4);
    b3v[1] = *(const float4*)(b3g + 16 + quad * 4);
    float b2r[8];
#pragma unroll
    for (int nt = 0; nt < 8; ++nt) b2r[nt] = b2g[nt * 16 + l16];

    // fspool weights for this lane's pair-row (element-invariant)
    const int pr = wv * 4 + quad;    // packed pair-row: channels 2pr (mu), 2pr+1 (logvar)
    float wE[8], wO[8];
    {
        const float* wsp = (const float*)((const char*)ws + WS_WSP);
        float4 e0 = *(const float4*)(wsp + (2 * pr) * 128 + l16 * 8);
        float4 e1 = *(const float4*)(wsp + (2 * pr) * 128 + l16 * 8 + 4);
        float4 o0 = *(const float4*)(wsp + (2 * pr + 1) * 128 + l16 * 8);
        float4 o1 = *(const float4*)(wsp + (2 * pr + 1) * 128 + l16 * 8 + 4);
        wE[0]=e0.x; wE[1]=e0.y; wE[2]=e0.z; wE[3]=e0.w; wE[4]=e1.x; wE[5]=e1.y; wE[6]=e1.z; wE[7]=e1.w;
        wO[0]=o0.x; wO[1]=o0.y; wO[2]=o0.z; wO[3]=o0.w; wO[4]=o1.x; wO[5]=o1.y; wO[6]=o1.z; wO[7]=o1.w;
    }
    __syncthreads();

    short*    scr   = (short*)(smem + L_SCR) + wv * (16 * 136);
    unsigned* szp   = (unsigned*)(smem + L_SZP);       // stride 132
    const float* sb1 = (const float*)(smem + L_B1);
    float*    spool = (float*)(smem + L_POOL);

    for (int e = 0; e < NB; ++e) {
        const int b = b0 + e;

        // ---------- GEMM1 (VALU, K=4): h1 A-frags, packed bf16 weights ----------
        const float4 xv0 = *(const float4*)(x + (size_t)b * 512 + (wv * 32 + l16) * 4);
        const float4 xv1 = *(const float4*)(x + (size_t)b * 512 + (wv * 32 + 16 + l16) * 4);
        union AF { unsigned u[4]; bf16x8 v; } a1[2][4];
#pragma unroll
        for (int kt = 0; kt < 4; ++kt) {
            const int k8 = kt * 32 + quad * 8;
            const float4 bb0 = *(const float4*)(sb1 + k8);
            const float4 bb1 = *(const float4*)(sb1 + k8 + 4);
            const float bias[8] = {bb0.x, bb0.y, bb0.z, bb0.w, bb1.x, bb1.y, bb1.z, bb1.w};
#pragma unroll
            for (int jp = 0; jp < 4; ++jp) {
                const uint4 wd = *(const uint4*)(smem + L_W1B + (k8 + 2 * jp) * 8);
                // h = k8+2jp: wd.x={w0,w1}, wd.y={w2,w3}; h+1: wd.z, wd.w
                const float wA0 = asf(wd.x << 16), wA1 = asf(wd.x & 0xffff0000u);
                const float wA2 = asf(wd.y << 16), wA3 = asf(wd.y & 0xffff0000u);
                const float wB0 = asf(wd.z << 16), wB1 = asf(wd.z & 0xffff0000u);
                const float wB2 = asf(wd.w << 16), wB3 = asf(wd.w & 0xffff0000u);
                float vA0 = fmaf(xv0.x, wA0, fmaf(xv0.y, wA1, fmaf(xv0.z, wA2, fmaf(xv0.w, wA3, bias[2*jp]))));
                float vA1 = fmaf(xv0.x, wB0, fmaf(xv0.y, wB1, fmaf(xv0.z, wB2, fmaf(xv0.w, wB3, bias[2*jp+1]))));
                float vB0 = fmaf(xv1.x, wA0, fmaf(xv1.y, wA1, fmaf(xv1.z, wA2, fmaf(xv1.w, wA3, bias[2*jp]))));
                float vB1 = fmaf(xv1.x, wB0, fmaf(xv1.y, wB1, fmaf(xv1.z, wB2, fmaf(xv1.w, wB3, bias[2*jp+1]))));
                a1[0][kt].u[jp] = packtr(fmaxf(vA0, 0.f), fmaxf(vA1, 0.f));
                a1[1][kt].u[jp] = packtr(fmaxf(vB0, 0.f), fmaxf(vB1, 0.f));
            }
        }

        // ---------- GEMM2 (MFMA): h2 = relu(h1 @ W2 + b2), bias pre-seeded ----------
        f32x4 acc2[2][8];
#pragma unroll
        for (int mt = 0; mt < 2; ++mt)
#pragma unroll
            for (int nt = 0; nt < 8; ++nt)
                acc2[mt][nt] = (f32x4){b2r[nt], b2r[nt], b2r[nt], b2r[nt]};
#pragma unroll
        for (int kt = 0; kt < 4; ++kt)
#pragma unroll
            for (int nt = 0; nt < 8; ++nt) {
                const int j = nt * 16 + l16;
                const int phys = (kt * 4 + quad) ^ l16;
                bf16x8 bf = *(const bf16x8*)(smem + j * 256 + phys * 16);
                acc2[0][nt] = __builtin_amdgcn_mfma_f32_16x16x32_bf16(a1[0][kt].v, bf, acc2[0][nt], 0, 0, 0);
                acc2[1][nt] = __builtin_amdgcn_mfma_f32_16x16x32_bf16(a1[1][kt].v, bf, acc2[1][nt], 0, 0, 0);
            }

        // ---------- GEMM3 transposed: z = W3T @ h2^T (+b3), via per-wave scr ----------
#pragma unroll
        for (int mt = 0; mt < 2; ++mt) {
#pragma unroll
            for (int nt = 0; nt < 8; ++nt) {
                const int col = nt * 16 + l16;
#pragma unroll
                for (int r = 0; r < 4; ++r)
                    scr[(quad * 4 + r) * 136 + col] = f2bf(fmaxf(acc2[mt][nt][r], 0.0f));  // RNE
            }
            asm volatile("s_waitcnt lgkmcnt(0)" ::: "memory");  // wave-local scr RAW

            bf16x8 a3[4];
#pragma unroll
            for (int kt = 0; kt < 4; ++kt)
                a3[kt] = *(const bf16x8*)(scr + l16 * 136 + kt * 32 + quad * 8);

            const int colbase = wv * 32 + mt * 16;
#pragma unroll
            for (int mt2 = 0; mt2 < 2; ++mt2) {
                f32x4 acc = (f32x4){b3v[mt2].x, b3v[mt2].y, b3v[mt2].z, b3v[mt2].w};
#pragma unroll
                for (int kt = 0; kt < 4; ++kt)
                    acc = __builtin_amdgcn_mfma_f32_16x16x32_bf16(w3f[mt2][kt], a3[kt], acc, 0, 0, 0);
                // lane holds z rows c = 16*mt2 + 4*quad + r, col p = colbase + l16
                const int prw = 8 * mt2 + 2 * quad;
                szp[prw * 132 + colbase + l16]       = pkrne(acc[0], acc[1]);  // RNE; lo=even c (mu)
                szp[(prw + 1) * 132 + colbase + l16] = pkrne(acc[2], acc[3]);
            }
            asm volatile("" ::: "memory");  // keep a3 reads ahead of next-mt scr writes
        }
        __syncthreads();  // all waves' z columns visible

        // ---------- packed-f16 bitonic sort, 8 elems/lane over 16-lane groups ----------
        // group = quad; virtual element index i = l16*8 + r; full sort => input order free
        unsigned v[8];
        {
            const unsigned* zp = szp + pr * 132 + l16 * 8;
            uint4 za = *(const uint4*)zp;
            uint4 zb = *(const uint4*)(zp + 4);
            v[0]=za.x; v[1]=za.y; v[2]=za.z; v[3]=za.w;
            v[4]=zb.x; v[5]=zb.y; v[6]=zb.z; v[7]=zb.w;
        }
        const int ib = l16 * 8;
#pragma unroll
        for (int k = 2; k <= 128; k <<= 1) {
#pragma unroll
            for (int j = 64; j >= 1; j >>= 1) {
                if (j >= k) continue;
                if (j >= 8) {                       // cross-lane (within 16-lane DPP row)
                    const bool km = ((ib & k) == 0) != ((ib & j) != 0);
                    const int lm = j >> 3;
#pragma unroll
                    for (int r = 0; r < 8; ++r) {
                        unsigned p = xlane(v[r], lm);
                        unsigned mx = pkmax(v[r], p), mn = pkmin(v[r], p);
                        v[r] = km ? mx : mn;
                    }
                } else if (k <= 4) {                // in-lane, static direction
#pragma unroll
                    for (int a = 0; a < 8; ++a) {
                        if (a & j) continue;
                        const int bx = a | j;
                        unsigned mx = pkmax(v[a], v[bx]), mn = pkmin(v[a], v[bx]);
                        if ((a & k) == 0) { v[a] = mx; v[bx] = mn; }
                        else              { v[a] = mn; v[bx] = mx; }
                    }
                } else {                            // in-lane, lane-dependent direction
                    const bool km = ((ib & k) == 0);
#pragma unroll
                    for (int a = 0; a < 8; ++a) {
                        if (a & j) continue;
                        const int bx = a | j;
                        unsigned mx = pkmax(v[a], v[bx]), mn = pkmin(v[a], v[bx]);
                        v[a] = km ? mx : mn;
                        v[bx] = km ? mn : mx;
                    }
                }
            }
        }

        // ---------- weighted sum + 16-lane group reduction (DPP) ----------
        float sE = 0.f, sO = 0.f;
#pragma unroll
        for (int r = 0; r < 8; ++r) {
            sE = fmaf(wE[r], h2f(v[r]), sE);
            sO = fmaf(wO[r], h2f(v[r] >> 16), sO);
        }
#pragma unroll
        for (int d = 8; d >= 1; d >>= 1) {
            sE += xlanef(sE, d);
            sO += xlanef(sO, d);
        }
        if (l16 == 0) {
            spool[e * 32 + 2 * pr]     = sE;
            spool[e * 32 + 2 * pr + 1] = sO;
        }
        __syncthreads();  // spool ready; protects szp WAR for next element
    }

    // ---------- batched coalesced epilogue (NB*16 == 256) ----------
    {
        const int e = tid >> 4, t = tid & 15;
        const float mu = spool[e * 32 + 2 * t];
        const float lv = spool[e * 32 + 2 * t + 1];
        const float ev = eps[(size_t)b0 * 16 + tid];
        const float smp = fmaf(ev, __expf(0.5f * lv), mu);
        out[(size_t)b0 * 16 + tid] = mu;
        out[(size_t)B_TOT * 16 + (size_t)b0 * 16 + tid] = lv;
        out[(size_t)2 * B_TOT * 16 + (size_t)b0 * 16 + tid] = smp;
    }
}

extern "C" void kernel_launch(void* const* d_in, const int* in_sizes, int n_in,
                              void* d_out, int out_size, void* d_ws, size_t ws_size,
                              hipStream_t stream) {
    const float* x   = (const float*)d_in[0];
    const float* W1  = (const float*)d_in[1];
    const float* b1  = (const float*)d_in[2];
    const float* W2  = (const float*)d_in[3];
    const float* b2  = (const float*)d_in[4];
    const float* W3  = (const float*)d_in[5];
    const float* b3  = (const float*)d_in[6];
    const float* pw  = (const float*)d_in[7];
    const float* eps = (const float*)d_in[8];
    float* out = (float*)d_out;

    prep_kernel<<<dim3(97), dim3(256), 0, stream>>>(W1, W2, W3, pw, d_ws);
    enc_kernel<<<dim3(B_TOT / NB), dim3(256), 0, stream>>>(x, b1, b2, b3, eps, d_ws, out);
}